// Round 1
// baseline (175.051 us; speedup 1.0000x reference)
//
#include <hip/hip_runtime.h>

#define D_  256
#define H1_ 256
#define H2_ 128
#define B_  2
#define LQ_ 512
#define LK_ 512

typedef float  f32x4  __attribute__((ext_vector_type(4)));
typedef __bf16 bf16x8 __attribute__((ext_vector_type(8)));

// ---- prep v2: projection with register tiles (8 rows x 4 h per thread,
// K-split 2). x-row loads are wave-uniform (64 lanes share (rg,kh)) ->
// scalar-cache friendly; W1 loads coalesced f32x4. Removes the old
// per-FMA LDS-broadcast storm. Blocks 128..255 build w2f (unchanged math).
__global__ __launch_bounds__(256) void prep_kernel(
    const float* __restrict__ query, const float* __restrict__ key,
    const float* __restrict__ W1, const float* __restrict__ b1,
    const float* __restrict__ W2,
    float* __restrict__ qp, float* __restrict__ kp, __bf16* __restrict__ w2f) {
  const int blk = blockIdx.x;
  const int tid = threadIdx.x;
  if (blk >= 128) {
    const int id   = (blk - 128) * 256 + tid;   // 0..32767
    const int j    = id & 7;
    const int lane = (id >> 3) & 63;
    const int frag = id >> 9;                   // 0..63
    const int nt = frag & 3;
    const int wn = (frag >> 2) & 1;
    const int ks = (frag >> 3) & 1;
    const int kc = frag >> 4;
    const int n = wn * 64 + nt * 16 + (lane & 15);
    const int k = kc * 64 + ks * 32 + ((lane >> 4) << 3) + j;
    w2f[id] = (__bf16)W2[k * H2_ + n];
    return;
  }
  __shared__ __align__(16) float part[16][H1_];   // 16 KB (kh=1 partials)
  const int row0 = blk * 16;
  const int sel  = row0 >> 10;                    // 0=query, 1=key
  const float* __restrict__ src = (sel ? key : query) + (row0 & 1023) * D_;
  const int hg = tid & 63;          // 4-h group (wave-invariant operand below)
  const int rg = (tid >> 6) & 1;    // 8-row group
  const int kh = tid >> 7;          // K half
  const float* __restrict__ w = W1 + sel * D_ * H1_ + kh * 128 * H1_ + hg * 4;
  const float* __restrict__ x = src + rg * 8 * D_ + kh * 128;
  f32x4 acc[8];
#pragma unroll
  for (int r = 0; r < 8; ++r) acc[r] = (f32x4){0.f, 0.f, 0.f, 0.f};
  for (int dd = 0; dd < 128; dd += 4) {
    f32x4 wv[4];
#pragma unroll
    for (int i = 0; i < 4; ++i) wv[i] = *(const f32x4*)(w + (dd + i) * H1_);
#pragma unroll
    for (int r = 0; r < 8; ++r) {
      const f32x4 xv = *(const f32x4*)(x + r * D_ + dd);  // wave-uniform addr
#pragma unroll
      for (int i = 0; i < 4; ++i) acc[r] += xv[i] * wv[i];
    }
  }
  if (kh == 1) {
#pragma unroll
    for (int r = 0; r < 8; ++r)
      *(f32x4*)(&part[rg * 8 + r][hg * 4]) = acc[r];
  }
  __syncthreads();
  if (kh == 0) {
    float* __restrict__ dst = (sel ? kp : qp) + (row0 & 1023) * H1_;
    f32x4 bv = (f32x4){0.f, 0.f, 0.f, 0.f};
    if (!sel) bv = *(const f32x4*)(b1 + hg * 4);   // fold b1 into qp
#pragma unroll
    for (int r = 0; r < 8; ++r) {
      const f32x4 res = acc[r] + *(const f32x4*)(&part[rg * 8 + r][hg * 4]) + bv;
      *(f32x4*)(dst + (rg * 8 + r) * H1_ + hg * 4) = res;
    }
  }
}

// ---- score v3: barrier-free MFMA main loop.
// M-tile = 256 pairs (16 q x 16 k), 4 waves; wave wv owns q-rows wv*4..+4,
// all 128 H2 cols (acc[4][8]). A-fragments built in registers directly from
// global qp/kp (A-tile row = ki = l16, k-slice = quad*8+j) -> no A LDS, no
// per-K-step barriers. w2f (fragment-linear, 64 KB) staged once into LDS;
// B-frag reads are contiguous ds_read_b128 (conflict-free). One barrier/block.
__global__ __launch_bounds__(256, 2) void score_kernel(
    const float* __restrict__ qp, const float* __restrict__ kp,
    const __bf16* __restrict__ w2f,
    const float* __restrict__ b2, const float* __restrict__ W3,
    const float* __restrict__ b3, float* __restrict__ scores) {
  __shared__ __align__(16) __bf16 w2lds[H1_ * H2_];   // 64 KB

  const int b  = blockIdx.z;
  const int q0 = blockIdx.y * 16;
  const int k0 = blockIdx.x * 16;
  const int tid  = threadIdx.x;
  const int wv   = tid >> 6;
  const int lane = tid & 63;
  const int quad = lane >> 4;
  const int l16  = lane & 15;

  {  // stage w2f -> LDS (linear copy, 16B/lane/iter, conflict-free)
    const f32x4* __restrict__ s4 = (const f32x4*)w2f;
    f32x4* d4 = (f32x4*)w2lds;
#pragma unroll
    for (int i = 0; i < 16; ++i)
      d4[i * 256 + tid] = s4[i * 256 + tid];
  }

  f32x4 acc[4][8];
#pragma unroll
  for (int mt = 0; mt < 4; ++mt)
#pragma unroll
    for (int nt = 0; nt < 8; ++nt)
      acc[mt][nt] = (f32x4){0.f, 0.f, 0.f, 0.f};

  const float* __restrict__ qpb = qp + (b * LQ_ + q0 + wv * 4) * H1_ + quad * 8;
  const float* __restrict__ kpb = kp + (b * LK_ + k0 + l16) * H1_ + quad * 8;

  __syncthreads();   // the only barrier

#pragma unroll
  for (int kc = 0; kc < 4; ++kc) {
#pragma unroll
    for (int ks = 0; ks < 2; ++ks) {
      const int col = kc * 64 + ks * 32;
      const f32x4 kv0 = *(const f32x4*)(kpb + col);
      const f32x4 kv1 = *(const f32x4*)(kpb + col + 4);
      bf16x8 bfr[8];
      const __bf16* fb = w2lds + (kc * 2 + ks) * 8 * 512 + lane * 8;
#pragma unroll
      for (int nt = 0; nt < 8; ++nt)
        bfr[nt] = *(const bf16x8*)(fb + nt * 512);
#pragma unroll
      for (int mt = 0; mt < 4; ++mt) {
        const f32x4 qv0 = *(const f32x4*)(qpb + mt * H1_ + col);
        const f32x4 qv1 = *(const f32x4*)(qpb + mt * H1_ + col + 4);
        bf16x8 a;
#pragma unroll
        for (int jj = 0; jj < 4; ++jj) {
          a[jj]     = (__bf16)fmaxf(qv0[jj] + kv0[jj], 0.f);
          a[jj + 4] = (__bf16)fmaxf(qv1[jj] + kv1[jj], 0.f);
        }
#pragma unroll
        for (int nt = 0; nt < 8; ++nt)
          acc[mt][nt] = __builtin_amdgcn_mfma_f32_16x16x32_bf16(
              a, bfr[nt], acc[mt][nt], 0, 0, 0);
      }
    }
  }

  // epilogue: h2 = relu(acc + b2); dot with W3 over all 128 cols (8 nt x l16)
  float part[4][4];
#pragma unroll
  for (int mt = 0; mt < 4; ++mt)
#pragma unroll
    for (int rg = 0; rg < 4; ++rg) part[mt][rg] = 0.f;
#pragma unroll
  for (int nt = 0; nt < 8; ++nt) {
    const int cn = (nt >> 2) * 64 + (nt & 3) * 16 + l16;
    const float b2v = b2[cn];
    const float w3v = W3[cn];
#pragma unroll
    for (int mt = 0; mt < 4; ++mt)
#pragma unroll
      for (int rg = 0; rg < 4; ++rg)
        part[mt][rg] += fmaxf(acc[mt][nt][rg] + b2v, 0.f) * w3v;
  }
#pragma unroll
  for (int off = 1; off < 16; off <<= 1)
#pragma unroll
    for (int mt = 0; mt < 4; ++mt)
#pragma unroll
      for (int rg = 0; rg < 4; ++rg)
        part[mt][rg] += __shfl_xor(part[mt][rg], off, 64);
  if (l16 == 0) {
    const float b3v = b3[0];
#pragma unroll
    for (int mt = 0; mt < 4; ++mt)
#pragma unroll
      for (int rg = 0; rg < 4; ++rg)
        scores[(b * LQ_ + q0 + wv * 4 + mt) * LK_ + k0 + quad * 4 + rg] =
            part[mt][rg] + b3v;
  }
}

// ---- smout v3 (unchanged): 256 blocks x 512 thr; block owns (b, 4 q-rows).
__global__ __launch_bounds__(512) void smout_kernel(
    const float* __restrict__ sc, float* __restrict__ attn,
    const int* __restrict__ mask, const float* __restrict__ value,
    float* __restrict__ out) {
  const int qg = blockIdx.x, b = blockIdx.y;
  const int tid = threadIdx.x;
  __shared__ __align__(16) float a_lds[LK_][4];   // 8 KB, [k][q]
  __shared__ __align__(16) f32x4 p_lds[7][4][64]; // 28 KB partials
  const int row0 = b * LQ_ + qg * 4;
  const int w = tid >> 6, lane = tid & 63;
  if (w < 4) {
    const float* __restrict__ srow = sc + (row0 + w) * LK_;
    const int*  __restrict__ mrow = mask + (row0 + w) * LK_;
    float v[8];
#pragma unroll
    for (int j = 0; j < 8; ++j) {
      float s = srow[lane + j * 64];
      if (mrow[lane + j * 64] == 0) s = -1e9f;
      v[j] = s;
    }
    float m = v[0];
#pragma unroll
    for (int j = 1; j < 8; ++j) m = fmaxf(m, v[j]);
#pragma unroll
    for (int off = 32; off; off >>= 1) m = fmaxf(m, __shfl_xor(m, off, 64));
    float sum = 0.f;
#pragma unroll
    for (int j = 0; j < 8; ++j) { v[j] = __expf(v[j] - m); sum += v[j]; }
#pragma unroll
    for (int off = 32; off; off >>= 1) sum += __shfl_xor(sum, off, 64);
    const float inv = 1.f / sum;
    float* __restrict__ arow = attn + (row0 + w) * LK_;
#pragma unroll
    for (int j = 0; j < 8; ++j) {
      const float p = v[j] * inv;
      a_lds[lane + j * 64][w] = p;
      arow[lane + j * 64] = p;
    }
  }
  __syncthreads();
  // phase 2
  const int kh2 = tid >> 6;             // 0..7 : 64-deep k chunk
  const int dv  = tid & 63;             // float4 group over d (256 = 64x4)
  f32x4 acc[4];
#pragma unroll
  for (int q = 0; q < 4; ++q) acc[q] = (f32x4){0.f, 0.f, 0.f, 0.f};
  const f32x4* __restrict__ vb4 = (const f32x4*)value + (b * LK_ + kh2 * 64) * 64 + dv;
#pragma unroll 4
  for (int k = 0; k < 64; ++k) {
    const f32x4 v4 = vb4[k * 64];
    const f32x4 p4 = *(const f32x4*)(&a_lds[kh2 * 64 + k][0]);
#pragma unroll
    for (int q = 0; q < 4; ++q) acc[q] += p4[q] * v4;
  }
  if (kh2 > 0) {
#pragma unroll
    for (int q = 0; q < 4; ++q) p_lds[kh2 - 1][q][dv] = acc[q];
  }
  __syncthreads();
  if (kh2 == 0) {
    f32x4* __restrict__ ob4 = (f32x4*)out + row0 * 64 + dv;
#pragma unroll
    for (int q = 0; q < 4; ++q) {
      f32x4 r = acc[q];
#pragma unroll
      for (int pp = 0; pp < 7; ++pp) r += p_lds[pp][q][dv];
      ob4[q * 64] = r;
    }
  }
}

extern "C" void kernel_launch(void* const* d_in, const int* in_sizes, int n_in,
                              void* d_out, int out_size, void* d_ws, size_t ws_size,
                              hipStream_t stream) {
  (void)in_sizes; (void)n_in; (void)out_size; (void)ws_size;
  const float* query = (const float*)d_in[0];
  const float* key   = (const float*)d_in[1];
  const float* value = (const float*)d_in[2];
  const int*   mask  = (const int*)d_in[3];
  const float* W1    = (const float*)d_in[4];
  const float* b1    = (const float*)d_in[5];
  const float* W2    = (const float*)d_in[6];
  const float* b2    = (const float*)d_in[7];
  const float* W3    = (const float*)d_in[8];
  const float* b3    = (const float*)d_in[9];

  float* out  = (float*)d_out;                 // (B,LQ,D)   = 262144 floats
  float* attn = out + B_ * LQ_ * D_;           // (B,LQ,LK)  = 524288 floats

  // ws: qp (1MB) + kp (1MB) + w2f (64KB) + sc scratch scores (2MB)
  float*  qp  = (float*)d_ws;
  float*  kp  = qp + B_ * LQ_ * H1_;
  __bf16* w2f = (__bf16*)(kp + B_ * LK_ * H1_);
  float*  sc  = (float*)(w2f + H2_ * H1_);

  prep_kernel<<<256, 256, 0, stream>>>(query, key, W1, b1, W2, qp, kp, w2f);
  dim3 gscore(LK_ / 16, LQ_ / 16, B_);
  score_kernel<<<gscore, 256, 0, stream>>>(qp, kp, w2f, b2, W3, b3, sc);
  smout_kernel<<<dim3(128, B_), 512, 0, stream>>>(sc, attn, mask, value, out);
}